// Round 21
// baseline (116.945 us; speedup 1.0000x reference)
//
#include <hip/hip_runtime.h>
#include <stdint.h>

// VectorQuantizer — f32 I/O confirmed. d_in[0]=z [16384,64], d_in[1]=e [8192,64];
// d_out f32: [z_q 16384*64][idx-as-float 16384]. d_ws = 256MB confirmed.
//
// FROZEN exact numerics (fixup path only):
//   sz,se: scalar pairwise-8; c: 4 lanes (k mod 4), mul/add separately rounded,
//   16-chunks ascending, reversed sub-blocks (+12,+8,+4,+0), hadd (q0+q1)+(q2+q3);
//   A=fl(sz+se); d=fl(A-2c); argmin strict-<, first (smallest) index wins.
//
// Round-21: eval v13 — J-LEVEL banding. r13-r20: eval's ~40-48us floor was
// exactly-evaluating ALL 128 j of selected chunks (3.4M exact dots). New: MFMA
// re-scan of candidate rows reproduces c_bf16 bit-identically; only j with
// c_bf16 >= rmax[row]-BAND get the exact fixup (~2/row, 65x less exact work).
// Capture bound: 2x bf16 err (4.7e-5) + lattice 7.6e-6 = 9.9e-5 < BAND=1.25e-4;
// all post-rounding tie candidates are hits -> first-index semantics preserved
// by the verified atomicMin((d_bits<<32)|j) combine. compact pads cand with the
// last id (64 slots) so gathered loads need no clamping; dups idempotent.

#define NROWS 16384
#define NE    8192
#define D     64
#define BN    128
#define NCH   (NE / BN)     // 64
#define BAND  1.25e-4f
#define CAND_CAP 16448      // 16384 + 64 pad

typedef __attribute__((ext_vector_type(8))) short short8;
typedef __attribute__((ext_vector_type(4))) float f32x4;

__device__ __forceinline__ uint32_t bf16rn(float f) {
    union { float f; uint32_t u; } c; c.f = f;
    return (c.u + 0x7FFFu + ((c.u >> 16) & 1u)) >> 16;
}
__device__ __forceinline__ uint32_t pk2(float lo, float hi) {
    return bf16rn(lo) | (bf16rn(hi) << 16);
}

// ---------- phase 0: fused convert + coalesced exact prep (verified) ----------
__global__ __launch_bounds__(256)
void vq_convert_prep(const float* __restrict__ z, const float* __restrict__ e,
                     uint32_t* __restrict__ zb, uint32_t* __restrict__ eb,
                     float* __restrict__ sz_arr, float* __restrict__ se_arr)
{
    if (blockIdx.x < 768) {
        const int i = blockIdx.x * 256 + threadIdx.x;
        const int nz = NROWS * D / 8;
        const int ne = NE * D / 8;
        if (i < nz) {
            const float4 a = ((const float4*)z)[i * 2];
            const float4 b = ((const float4*)z)[i * 2 + 1];
            uint4 o; o.x = pk2(a.x, a.y); o.y = pk2(a.z, a.w);
            o.z = pk2(b.x, b.y); o.w = pk2(b.z, b.w);
            ((uint4*)zb)[i] = o;
        } else if (i < nz + ne) {
            const int k = i - nz;
            const float4 a = ((const float4*)e)[k * 2];
            const float4 b = ((const float4*)e)[k * 2 + 1];
            uint4 o; o.x = pk2(a.x, a.y); o.y = pk2(a.z, a.w);
            o.z = pk2(b.x, b.y); o.w = pk2(b.z, b.w);
            ((uint4*)eb)[k] = o;
        }
    } else {
        const int pb   = blockIdx.x - 768;
        const int wave = threadIdx.x >> 6, lane = threadIdx.x & 63;
        const int g    = lane & 7;
        const int grow = pb * 32 + wave * 8 + (lane >> 3);
        const float* src = (grow < NROWS) ? z + (size_t)grow * D
                                          : e + (size_t)(grow - NROWS) * D;
        float acc = 0.f;
        #pragma unroll
        for (int i = 0; i < 8; ++i) {
            const float x = src[i * 8 + g];
            acc = __fadd_rn(acc, __fmul_rn(x, x));
        }
        const float s1 = __fadd_rn(acc, __shfl_xor(acc, 1, 64));
        const float s2 = __fadd_rn(s1,  __shfl_xor(s1, 2, 64));
        const float s4 = __fadd_rn(s2,  __shfl_xor(s2, 4, 64));
        if (g == 0) {
            if (grow < NROWS) sz_arr[grow] = s4;
            else              se_arr[grow - NROWS] = s4;
        }
    }
}

// ---------- phase 1: MFMA GEMM + per-(row,chunk) max (verified, unchanged) ----------
__global__ __launch_bounds__(256)
void vq_scan_mfma(const uint16_t* __restrict__ zb, const uint16_t* __restrict__ eb,
                  float* __restrict__ cmax)
{
    __shared__ uint16_t elds[BN][72];
    __shared__ float    rmld[4][64][20];

    const int tid  = threadIdx.x;
    const int lane = tid & 63, w = tid >> 6;
    const int mb   = blockIdx.x >> 5;
    const int jb   = blockIdx.x & 31;
    const int row0 = mb * 256 + w * 64;
    const int l15  = lane & 15, l4 = lane >> 4;

    short8 af[4][2];
    #pragma unroll
    for (int m = 0; m < 4; ++m)
        #pragma unroll
        for (int h = 0; h < 2; ++h)
            af[m][h] = *(const short8*)(zb + (size_t)(row0 + m * 16 + l15) * D + h * 32 + l4 * 8);

    const f32x4 z4 = {0.f, 0.f, 0.f, 0.f};

    #pragma unroll 1
    for (int c = 0; c < 2; ++c) {
        const int j0 = jb * 256 + c * BN;
        {
            const int srow = tid >> 1, shalf = tid & 1;
            const uint16_t* sp = eb + (size_t)(j0 + srow) * D + shalf * 32;
            uint16_t* dp = &elds[srow][shalf * 32];
            #pragma unroll
            for (int q = 0; q < 4; ++q)
                *(short8*)(dp + q * 8) = *(const short8*)(sp + q * 8);
        }
        __syncthreads();

        f32x4 rm[4];
        #pragma unroll
        for (int m = 0; m < 4; ++m) rm[m] = {-3.0e38f, -3.0e38f, -3.0e38f, -3.0e38f};

        #pragma unroll 1
        for (int n = 0; n < 8; ++n) {
            const uint16_t* bp = &elds[n * 16 + l15][l4 * 8];
            const short8 b0 = *(const short8*)(bp);
            const short8 b1 = *(const short8*)(bp + 32);
            #pragma unroll
            for (int m = 0; m < 4; ++m) {
                f32x4 acc = __builtin_amdgcn_mfma_f32_16x16x32_bf16(af[m][0], b0, z4, 0, 0, 0);
                acc = __builtin_amdgcn_mfma_f32_16x16x32_bf16(af[m][1], b1, acc, 0, 0, 0);
                #pragma unroll
                for (int r = 0; r < 4; ++r) rm[m][r] = fmaxf(rm[m][r], acc[r]);
            }
        }

        #pragma unroll
        for (int m = 0; m < 4; ++m)
            *(f32x4*)&rmld[w][lane][m * 4] = rm[m];
        const int r  = lane;
        const int mm = r >> 4, rg = r & 3, lg = ((r & 15) >> 2) * 16;
        float v = rmld[w][lg][mm * 4 + rg];
        #pragma unroll
        for (int i = 1; i < 16; ++i) v = fmaxf(v, rmld[w][lg + i][mm * 4 + rg]);
        cmax[(size_t)(row0 + r) * NCH + (jb * 2 + c)] = v;
        __syncthreads();
    }
}

// ---------- phase 2a: band-select -> per-row bitmask + rmax (no atomics) ----------
__global__ __launch_bounds__(256)
void vq_select_mask(const float* __restrict__ cmax,
                    unsigned long long* __restrict__ mask,
                    float* __restrict__ rmax_arr,
                    unsigned long long* __restrict__ packed)
{
    const int lane = threadIdx.x & 63, w = threadIdx.x >> 6;
    const int row = blockIdx.x * 4 + w;

    const float ci = cmax[(size_t)row * NCH + lane];   // lane = chunk
    float cm = ci;
    #pragma unroll
    for (int o = 1; o < 64; o <<= 1) cm = fmaxf(cm, __shfl_xor(cm, o, 64));
    const unsigned long long m = __ballot(ci >= cm - BAND);
    if (lane == 0) {
        mask[row] = m;
        rmax_arr[row] = cm;
        packed[row] = 0xFFFFFFFFFFFFFFFFull;
    }
}

// ---------- phase 2b: compaction + 64-slot pad (barrier-free core) ----------
__global__ __launch_bounds__(256)
void vq_compact(const unsigned long long* __restrict__ mask,
                int* __restrict__ cand, unsigned int* __restrict__ counts)
{
    __shared__ unsigned int cnt_lds;
    const int ch = blockIdx.x;
    const int t = threadIdx.x, lane = t & 63;
    if (t == 0) cnt_lds = 0;
    __syncthreads();

    #pragma unroll 1
    for (int r0 = 0; r0 < NROWS; r0 += 256) {
        const int row = r0 + t;
        const bool hit = (mask[row] >> ch) & 1ull;
        const unsigned long long b = __ballot(hit);
        unsigned int base = 0;
        if (lane == 0 && b) base = atomicAdd(&cnt_lds, (unsigned int)__popcll(b));
        base = (unsigned int)__shfl((int)base, 0, 64);
        if (hit) {
            const unsigned int rank = (unsigned int)__popcll(b & ((1ull << lane) - 1ull));
            cand[(size_t)ch * CAND_CAP + base + rank] = row;
        }
    }
    __syncthreads();
    const unsigned int cnt = cnt_lds;
    if (t == 0) counts[ch] = cnt;
    if (cnt > 0 && t < 64)   // pad so eval's gathered loads need no clamping
        cand[(size_t)ch * CAND_CAP + cnt + t] = cand[(size_t)ch * CAND_CAP + cnt - 1];
}

// ---------- exact fixup (frozen numerics; rare) ----------
__device__ __attribute__((noinline))
void vq_fixup(int row, int j,
              const float* __restrict__ z, const float* __restrict__ e,
              const float* __restrict__ sz_arr, const float* __restrict__ se_arr,
              unsigned long long* __restrict__ packed)
{
    const float* zp = z + (size_t)row * D;
    const float* ep = e + (size_t)j * D;
    float q0 = 0.f, q1 = 0.f, q2 = 0.f, q3 = 0.f;
    #pragma unroll
    for (int cc = 0; cc < 4; ++cc) {
        #pragma unroll
        for (int sb = 3; sb >= 0; --sb) {
            const int b = cc * 16 + sb * 4;
            const float4 zv = *(const float4*)(zp + b);
            const float4 ev = *(const float4*)(ep + b);
            q0 = __fadd_rn(q0, __fmul_rn(zv.x, ev.x));
            q1 = __fadd_rn(q1, __fmul_rn(zv.y, ev.y));
            q2 = __fadd_rn(q2, __fmul_rn(zv.z, ev.z));
            q3 = __fadd_rn(q3, __fmul_rn(zv.w, ev.w));
        }
    }
    const float c = __fadd_rn(__fadd_rn(q0, q1), __fadd_rn(q2, q3));
    const float A = __fadd_rn(sz_arr[row], se_arr[j]);     // fl(sz + se)
    const float d = __fsub_rn(A, __fadd_rn(c, c));          // fl(A - 2c)
    const unsigned long long key =
        ((unsigned long long)__float_as_uint(d) << 32) | (unsigned int)j;
    atomicMin(packed + row, key);   // d>0 -> monotone bits; order-invariant
}

// ---------- phase 2c: eval v13 — MFMA re-scan of candidates + sparse fixup ----------
__global__ __launch_bounds__(256)
void vq_eval(const uint16_t* __restrict__ zb, const uint16_t* __restrict__ eb,
             const float* __restrict__ z, const float* __restrict__ e,
             const float* __restrict__ sz_arr, const float* __restrict__ se_arr,
             const float* __restrict__ rmax_arr,
             const unsigned int* __restrict__ counts, const int* __restrict__ cand,
             unsigned long long* __restrict__ packed)
{
    __shared__ uint16_t elds[BN][72];     // 18 KB, scan-verified layout

    const int ch  = blockIdx.x;           // 0..63
    const int grp = blockIdx.y;           // 0..15
    const int tid = threadIdx.x;
    const int lane = tid & 63, w = tid >> 6;
    const int l15 = lane & 15, l4 = lane >> 4;

    const unsigned int cnt = counts[ch];
    if ((unsigned int)(grp * 64) >= cnt) return;

    {   // stage chunk's bf16 e-tile (identical layout/pattern to scan)
        const int srow = tid >> 1, shalf = tid & 1;
        const uint16_t* sp = eb + (size_t)(ch * BN + srow) * D + shalf * 32;
        uint16_t* dp = &elds[srow][shalf * 32];
        #pragma unroll
        for (int q = 0; q < 4; ++q)
            *(short8*)(dp + q * 8) = *(const short8*)(sp + q * 8);
    }
    __syncthreads();   // elds read-only afterwards

    const int jb0 = ch * BN;
    const f32x4 zero4 = {0.f, 0.f, 0.f, 0.f};
    const int* cl = cand + (size_t)ch * CAND_CAP;

    #pragma unroll 1
    for (int g = grp; (unsigned int)(g * 64) < cnt; g += 16) {
        const int ibase = g * 64 + w * 16;
        // A-frag: gathered candidate row (pad makes ibase+l15 always valid)
        const int arow = cl[ibase + l15];
        const short8 af0 = *(const short8*)(zb + (size_t)arow * D +      l4 * 8);
        const short8 af1 = *(const short8*)(zb + (size_t)arow * D + 32 + l4 * 8);
        // C-side rows this lane owns (C layout: row = l4*4 + reg, col = l15)
        const int4 cd4 = *(const int4*)(cl + ibase + l4 * 4);
        const float th0 = rmax_arr[cd4.x] - BAND;
        const float th1 = rmax_arr[cd4.y] - BAND;
        const float th2 = rmax_arr[cd4.z] - BAND;
        const float th3 = rmax_arr[cd4.w] - BAND;

        #pragma unroll 1
        for (int n = 0; n < 8; ++n) {
            const uint16_t* bp = &elds[n * 16 + l15][l4 * 8];
            const short8 b0 = *(const short8*)(bp);
            const short8 b1 = *(const short8*)(bp + 32);
            f32x4 acc = __builtin_amdgcn_mfma_f32_16x16x32_bf16(af0, b0, zero4, 0, 0, 0);
            acc = __builtin_amdgcn_mfma_f32_16x16x32_bf16(af1, b1, acc, 0, 0, 0);
            const int jcol = jb0 + n * 16 + l15;
            if (acc[0] >= th0) vq_fixup(cd4.x, jcol, z, e, sz_arr, se_arr, packed);
            if (acc[1] >= th1) vq_fixup(cd4.y, jcol, z, e, sz_arr, se_arr, packed);
            if (acc[2] >= th2) vq_fixup(cd4.z, jcol, z, e, sz_arr, se_arr, packed);
            if (acc[3] >= th3) vq_fixup(cd4.w, jcol, z, e, sz_arr, se_arr, packed);
        }
    }
}

// ---------- phase 3: z_q + idx from packed ----------
__global__ __launch_bounds__(256)
void vq_zq(const float* __restrict__ z, const float* __restrict__ e,
           const unsigned long long* __restrict__ packed, float* __restrict__ out)
{
    const size_t m = (size_t)blockIdx.x * 256 + threadIdx.x;
    const int r = (int)(m >> 6), k = (int)(m & 63);
    const int sel = (int)(packed[r] & 0xFFFFFFFFull);
    const float zv = z[m];
    const float ev = e[(size_t)sel * D + k];
    out[m] = __fadd_rn(zv, __fsub_rn(ev, zv));
    if (k == 0) out[(size_t)NROWS * D + r] = (float)sel;
}

extern "C" void kernel_launch(void* const* d_in, const int* in_sizes, int n_in,
                              void* d_out, int out_size, void* d_ws, size_t ws_size,
                              hipStream_t stream)
{
    const float* z = (const float*)d_in[0];
    const float* e = (const float*)d_in[1];
    float* out = (float*)d_out;

    char* ws = (char*)d_ws;
    const size_t MB = 1024 * 1024, KB = 1024;
    uint16_t* zb               = (uint16_t*)(ws);                         // 0..2 MB
    uint16_t* eb               = (uint16_t*)(ws + 2 * MB);                // 2..3 MB
    float* cmaxb               = (float*)(ws + 3 * MB);                   // 3..7 MB
    float* sz_arr              = (float*)(ws + 7 * MB);                   // 64 KB
    float* se_arr              = (float*)(ws + 7 * MB + 64 * KB);         // 32 KB
    unsigned long long* mask   = (unsigned long long*)(ws + 7 * MB + 128 * KB); // 128 KB
    unsigned long long* packed = (unsigned long long*)(ws + 7 * MB + 256 * KB); // 128 KB
    unsigned int* counts       = (unsigned int*)(ws + 7 * MB + 384 * KB); // 256 B
    float* rmax_arr            = (float*)(ws + 7 * MB + 512 * KB);        // 64 KB
    int* cand                  = (int*)(ws + 8 * MB);                     // ~4.2 MB

    vq_convert_prep<<<dim3(1536),            dim3(256), 0, stream>>>(z, e, (uint32_t*)zb, (uint32_t*)eb, sz_arr, se_arr);
    vq_scan_mfma   <<<dim3(2048),            dim3(256), 0, stream>>>(zb, eb, cmaxb);
    vq_select_mask <<<dim3(NROWS / 4),       dim3(256), 0, stream>>>(cmaxb, mask, rmax_arr, packed);
    vq_compact     <<<dim3(NCH),             dim3(256), 0, stream>>>(mask, cand, counts);
    vq_eval        <<<dim3(NCH, 16),         dim3(256), 0, stream>>>(zb, eb, z, e, sz_arr, se_arr, rmax_arr, counts, cand, packed);
    vq_zq          <<<dim3(NROWS * D / 256), dim3(256), 0, stream>>>(z, e, packed, out);
}

// Round 22
// 108.085 us; speedup vs baseline: 1.0820x; 1.0820x over previous
//
#include <hip/hip_runtime.h>
#include <stdint.h>

// VectorQuantizer — f32 I/O confirmed. d_in[0]=z [16384,64], d_in[1]=e [8192,64];
// d_out f32: [z_q 16384*64][idx-as-float 16384]. d_ws = 256MB confirmed.
//
// FROZEN exact numerics (eval path only):
//   sz,se: scalar pairwise-8; c: 4 lanes (k mod 4), mul/add separately rounded,
//   16-chunks ascending, reversed sub-blocks (+12,+8,+4,+0), hadd (q0+q1)+(q2+q3);
//   A=fl(sz+se); d=fl(A-2c); argmin strict-<, first (smallest) index wins.
//
// Round-22: eval reverted to r18's verified v10 (39.6us, best total 105.7).
// SCAN rewritten: r18 accounting shows scan ~30-45us (never in top-5, cutoff
// 39.5) with structural waste: 38KB LDS (elds 18K + rmld 20K transpose-reduce)
// -> 4 blocks/CU, and 2 chunks serialized through 4 barriers per block. New:
// one chunk/block (grid 64x64, single barrier), rmld replaced by __shfl_xor
// max over the 16 column-lanes (offsets 1,2,4,8 stay in the l4 group; max is
// order-invariant -> cmax bit-identical) -> 18KB LDS, 8 blocks/CU.

#define NROWS 16384
#define NE    8192
#define D     64
#define BN    128
#define NCH   (NE / BN)     // 64
#define BAND  1.25e-4f
#define CAND_CAP 16384
#define EVG   16            // item-groups per chunk (eval v10)
#define ELS   68            // eval LDS row stride (floats)

typedef __attribute__((ext_vector_type(8))) short short8;
typedef __attribute__((ext_vector_type(4))) float f32x4;

__device__ __forceinline__ uint32_t bf16rn(float f) {
    union { float f; uint32_t u; } c; c.f = f;
    return (c.u + 0x7FFFu + ((c.u >> 16) & 1u)) >> 16;
}
__device__ __forceinline__ uint32_t pk2(float lo, float hi) {
    return bf16rn(lo) | (bf16rn(hi) << 16);
}
#define RL(v, l) __uint_as_float(__builtin_amdgcn_readlane(__float_as_uint(v), (l)))

// ---------- phase 0: fused convert + coalesced exact prep (verified) ----------
__global__ __launch_bounds__(256)
void vq_convert_prep(const float* __restrict__ z, const float* __restrict__ e,
                     uint32_t* __restrict__ zb, uint32_t* __restrict__ eb,
                     float* __restrict__ sz_arr, float* __restrict__ se_arr)
{
    if (blockIdx.x < 768) {
        const int i = blockIdx.x * 256 + threadIdx.x;
        const int nz = NROWS * D / 8;
        const int ne = NE * D / 8;
        if (i < nz) {
            const float4 a = ((const float4*)z)[i * 2];
            const float4 b = ((const float4*)z)[i * 2 + 1];
            uint4 o; o.x = pk2(a.x, a.y); o.y = pk2(a.z, a.w);
            o.z = pk2(b.x, b.y); o.w = pk2(b.z, b.w);
            ((uint4*)zb)[i] = o;
        } else if (i < nz + ne) {
            const int k = i - nz;
            const float4 a = ((const float4*)e)[k * 2];
            const float4 b = ((const float4*)e)[k * 2 + 1];
            uint4 o; o.x = pk2(a.x, a.y); o.y = pk2(a.z, a.w);
            o.z = pk2(b.x, b.y); o.w = pk2(b.z, b.w);
            ((uint4*)eb)[k] = o;
        }
    } else {
        const int pb   = blockIdx.x - 768;
        const int wave = threadIdx.x >> 6, lane = threadIdx.x & 63;
        const int g    = lane & 7;
        const int grow = pb * 32 + wave * 8 + (lane >> 3);
        const float* src = (grow < NROWS) ? z + (size_t)grow * D
                                          : e + (size_t)(grow - NROWS) * D;
        float acc = 0.f;
        #pragma unroll
        for (int i = 0; i < 8; ++i) {
            const float x = src[i * 8 + g];
            acc = __fadd_rn(acc, __fmul_rn(x, x));
        }
        const float s1 = __fadd_rn(acc, __shfl_xor(acc, 1, 64));
        const float s2 = __fadd_rn(s1,  __shfl_xor(s1, 2, 64));
        const float s4 = __fadd_rn(s2,  __shfl_xor(s2, 4, 64));
        if (g == 0) {
            if (grow < NROWS) sz_arr[grow] = s4;
            else              se_arr[grow - NROWS] = s4;
        }
    }
}

// ---------- phase 1: scan v2 — one chunk/block, shfl-max reduce, 18KB LDS ----------
__global__ __launch_bounds__(256)
void vq_scan_mfma(const uint16_t* __restrict__ zb, const uint16_t* __restrict__ eb,
                  float* __restrict__ cmax)
{
    __shared__ uint16_t elds[BN][72];    // 18 KB; pad keeps b-reads 2-way (free)

    const int tid  = threadIdx.x;
    const int lane = tid & 63, w = tid >> 6;
    const int mb   = blockIdx.x >> 6;    // row-block 0..63
    const int ch   = blockIdx.x & 63;    // chunk 0..63
    const int row0 = mb * 256 + w * 64;
    const int l15  = lane & 15, l4 = lane >> 4;

    {   // stage this chunk's 128 e-rows (16 KB), coalesced
        const int srow = tid >> 1, shalf = tid & 1;
        const uint16_t* sp = eb + (size_t)(ch * BN + srow) * D + shalf * 32;
        uint16_t* dp = &elds[srow][shalf * 32];
        #pragma unroll
        for (int q = 0; q < 4; ++q)
            *(short8*)(dp + q * 8) = *(const short8*)(sp + q * 8);
    }

    short8 af[4][2];
    #pragma unroll
    for (int m = 0; m < 4; ++m)
        #pragma unroll
        for (int h = 0; h < 2; ++h)
            af[m][h] = *(const short8*)(zb + (size_t)(row0 + m * 16 + l15) * D + h * 32 + l4 * 8);

    __syncthreads();   // single barrier; elds read-only afterwards

    const f32x4 z4 = {0.f, 0.f, 0.f, 0.f};
    f32x4 rm[4];
    #pragma unroll
    for (int m = 0; m < 4; ++m) rm[m] = {-3.0e38f, -3.0e38f, -3.0e38f, -3.0e38f};

    #pragma unroll 1
    for (int n = 0; n < 8; ++n) {
        const uint16_t* bp = &elds[n * 16 + l15][l4 * 8];
        const short8 b0 = *(const short8*)(bp);
        const short8 b1 = *(const short8*)(bp + 32);
        #pragma unroll
        for (int m = 0; m < 4; ++m) {
            f32x4 acc = __builtin_amdgcn_mfma_f32_16x16x32_bf16(af[m][0], b0, z4, 0, 0, 0);
            acc = __builtin_amdgcn_mfma_f32_16x16x32_bf16(af[m][1], b1, acc, 0, 0, 0);
            #pragma unroll
            for (int r = 0; r < 4; ++r) rm[m][r] = fmaxf(rm[m][r], acc[r]);
        }
    }

    // max over the 16 column-lanes (xor bits 0..3 stay within each l4 group);
    // max is order-invariant -> cmax bit-identical to the old LDS reduce.
    #pragma unroll
    for (int m = 0; m < 4; ++m) {
        #pragma unroll
        for (int r = 0; r < 4; ++r) {
            #pragma unroll
            for (int o = 1; o < 16; o <<= 1)
                rm[m][r] = fmaxf(rm[m][r], __shfl_xor(rm[m][r], o, 64));
        }
        if (l15 < 4) {   // C layout: row = m*16 + l4*4 + reg, reg selected by l15
            const float v = (l15 == 0) ? rm[m][0] : (l15 == 1) ? rm[m][1]
                          : (l15 == 2) ? rm[m][2] : rm[m][3];
            cmax[(size_t)(row0 + m * 16 + l4 * 4 + l15) * NCH + ch] = v;
        }
    }
}

// ---------- phase 2a: band-select -> per-row bitmask (no atomics) ----------
__global__ __launch_bounds__(256)
void vq_select_mask(const float* __restrict__ cmax,
                    unsigned long long* __restrict__ mask,
                    unsigned long long* __restrict__ packed)
{
    const int lane = threadIdx.x & 63, w = threadIdx.x >> 6;
    const int row = blockIdx.x * 4 + w;

    const float ci = cmax[(size_t)row * NCH + lane];   // lane = chunk
    float cm = ci;
    #pragma unroll
    for (int o = 1; o < 64; o <<= 1) cm = fmaxf(cm, __shfl_xor(cm, o, 64));
    const unsigned long long m = __ballot(ci >= cm - BAND);
    if (lane == 0) { mask[row] = m; packed[row] = 0xFFFFFFFFFFFFFFFFull; }
}

// ---------- phase 2b: compaction (barrier-free, LDS atomic, unordered) ----------
__global__ __launch_bounds__(256)
void vq_compact(const unsigned long long* __restrict__ mask,
                int* __restrict__ cand, unsigned int* __restrict__ counts)
{
    __shared__ unsigned int cnt_lds;
    const int ch = blockIdx.x;
    const int t = threadIdx.x, lane = t & 63;
    if (t == 0) cnt_lds = 0;
    __syncthreads();

    #pragma unroll 1
    for (int r0 = 0; r0 < NROWS; r0 += 256) {
        const int row = r0 + t;
        const bool hit = (mask[row] >> ch) & 1ull;
        const unsigned long long b = __ballot(hit);
        unsigned int base = 0;
        if (lane == 0 && b) base = atomicAdd(&cnt_lds, (unsigned int)__popcll(b));
        base = (unsigned int)__shfl((int)base, 0, 64);
        if (hit) {
            const unsigned int rank = (unsigned int)__popcll(b & ((1ull << lane) - 1ull));
            cand[(size_t)ch * CAND_CAP + base + rank] = row;
        }
    }
    __syncthreads();
    if (t == 0) counts[ch] = cnt_lds;
}

// ---------- phase 2c: eval v10 (r18-verified, 39.6us) ----------
__global__ __launch_bounds__(256)
void vq_eval(const float* __restrict__ z, const float* __restrict__ e,
             const float* __restrict__ sz_arr, const float* __restrict__ se_arr,
             const unsigned int* __restrict__ counts, const int* __restrict__ cand,
             unsigned long long* __restrict__ packed)
{
    __shared__ float el[BN * ELS];       // 34 KB e-chunk, stride-68 b128-optimal

    const int ch  = blockIdx.x;          // 0..63
    const int grp = blockIdx.y;          // 0..EVG-1
    const int t   = threadIdx.x, lane = t & 63, w = t >> 6;

    const unsigned int cnt = counts[ch];
    const int base0 = grp * 16;
    if ((unsigned int)base0 >= cnt) return;

    {   // stage e-chunk: coalesced float4 reads -> b128 LDS writes
        const float4* src4 = (const float4*)(e + (size_t)ch * BN * D);
        #pragma unroll
        for (int v = t; v < BN * D / 4; v += 256) {
            const int row = v >> 4, c4 = (v & 15) << 2;
            *(float4*)&el[row * ELS + c4] = src4[v];
        }
    }
    __syncthreads();   // only barrier; el is read-only afterwards

    const int jbase = ch * BN;
    const float* e0 = &el[lane * ELS];            // j = jbase + lane
    const float* e1 = &el[(lane + 64) * ELS];     // j = jbase + 64 + lane
    const float se0 = se_arr[jbase + lane];
    const float se1 = se_arr[jbase + 64 + lane];
    const int gsrc  = lane & 15;                  // granule this lane sources
    const int isrc  = lane >> 4;                  // item this lane sources (0..3)

    for (unsigned int s0 = (unsigned int)(base0 + w * 4); s0 < cnt; s0 += (unsigned int)EVG * 16u) {
        int rows[4]; float szs[4];
        #pragma unroll
        for (int it = 0; it < 4; ++it) {
            unsigned int si = s0 + it; if (si >= cnt) si = cnt - 1;   // dup: idempotent
            rows[it] = cand[(size_t)ch * CAND_CAP + si];   // uniform -> s_load
            szs[it]  = sz_arr[rows[it]];                   // uniform -> s_load
        }
        const float4 zf = *(const float4*)(z + (size_t)rows[isrc] * D + gsrc * 4);

        float acc[4][2][4];
        #pragma unroll
        for (int it = 0; it < 4; ++it)
            #pragma unroll
            for (int jr = 0; jr < 2; ++jr)
                #pragma unroll
                for (int q = 0; q < 4; ++q) acc[it][jr][q] = 0.f;

        // frozen order: cc ascending; granules +12,+8,+4,+0; q_i gets k===i mod 4
        #pragma unroll
        for (int cc = 0; cc < 4; ++cc) {
            #pragma unroll
            for (int sb = 3; sb >= 0; --sb) {
                const int b = cc * 16 + sb * 4;
                const int g = cc * 4 + sb;
                const float4 ef0 = *(const float4*)&e0[b]; // ds_read_b128
                const float4 ef1 = *(const float4*)&e1[b]; // ds_read_b128
                #pragma unroll
                for (int it = 0; it < 4; ++it) {
                    const int sl = it * 16 + g;            // compile-time lane
                    const float zx = RL(zf.x, sl);
                    const float zy = RL(zf.y, sl);
                    const float zz = RL(zf.z, sl);
                    const float zw = RL(zf.w, sl);
                    acc[it][0][0] = __fadd_rn(acc[it][0][0], __fmul_rn(zx, ef0.x));
                    acc[it][0][1] = __fadd_rn(acc[it][0][1], __fmul_rn(zy, ef0.y));
                    acc[it][0][2] = __fadd_rn(acc[it][0][2], __fmul_rn(zz, ef0.z));
                    acc[it][0][3] = __fadd_rn(acc[it][0][3], __fmul_rn(zw, ef0.w));
                    acc[it][1][0] = __fadd_rn(acc[it][1][0], __fmul_rn(zx, ef1.x));
                    acc[it][1][1] = __fadd_rn(acc[it][1][1], __fmul_rn(zy, ef1.y));
                    acc[it][1][2] = __fadd_rn(acc[it][1][2], __fmul_rn(zz, ef1.z));
                    acc[it][1][3] = __fadd_rn(acc[it][1][3], __fmul_rn(zw, ef1.w));
                }
            }
        }

        #pragma unroll
        for (int it = 0; it < 4; ++it) {
            const float c0 = __fadd_rn(__fadd_rn(acc[it][0][0], acc[it][0][1]),
                                       __fadd_rn(acc[it][0][2], acc[it][0][3]));
            const float c1 = __fadd_rn(__fadd_rn(acc[it][1][0], acc[it][1][1]),
                                       __fadd_rn(acc[it][1][2], acc[it][1][3]));
            const float A0 = __fadd_rn(szs[it], se0);
            const float A1 = __fadd_rn(szs[it], se1);
            float d  = __fsub_rn(A0, __fadd_rn(c0, c0));
            int   bj = jbase + lane;
            const float d1 = __fsub_rn(A1, __fadd_rn(c1, c1));
            if (d1 < d) { d = d1; bj = jbase + 64 + lane; }   // j0<j1: tie keeps j0
            #pragma unroll
            for (int o = 1; o < 64; o <<= 1) {                // argmin, first-index ties
                const float od = __shfl_xor(d, o, 64);
                const int   oj = __shfl_xor(bj, o, 64);
                if (od < d || (od == d && oj < bj)) { d = od; bj = oj; }
            }
            if (lane == 0) {
                const unsigned long long key =
                    ((unsigned long long)__float_as_uint(d) << 32) | (unsigned int)bj;
                atomicMin(packed + rows[it], key);   // d>0 -> monotone; deterministic
            }
        }
    }
}

// ---------- phase 3: z_q + idx from packed ----------
__global__ __launch_bounds__(256)
void vq_zq(const float* __restrict__ z, const float* __restrict__ e,
           const unsigned long long* __restrict__ packed, float* __restrict__ out)
{
    const size_t m = (size_t)blockIdx.x * 256 + threadIdx.x;
    const int r = (int)(m >> 6), k = (int)(m & 63);
    const int sel = (int)(packed[r] & 0xFFFFFFFFull);
    const float zv = z[m];
    const float ev = e[(size_t)sel * D + k];
    out[m] = __fadd_rn(zv, __fsub_rn(ev, zv));
    if (k == 0) out[(size_t)NROWS * D + r] = (float)sel;
}

extern "C" void kernel_launch(void* const* d_in, const int* in_sizes, int n_in,
                              void* d_out, int out_size, void* d_ws, size_t ws_size,
                              hipStream_t stream)
{
    const float* z = (const float*)d_in[0];
    const float* e = (const float*)d_in[1];
    float* out = (float*)d_out;

    char* ws = (char*)d_ws;
    const size_t MB = 1024 * 1024, KB = 1024;
    uint16_t* zb               = (uint16_t*)(ws);                         // 0..2 MB
    uint16_t* eb               = (uint16_t*)(ws + 2 * MB);                // 2..3 MB
    float* cmaxb               = (float*)(ws + 3 * MB);                   // 3..7 MB
    float* sz_arr              = (float*)(ws + 7 * MB);                   // 64 KB
    float* se_arr              = (float*)(ws + 7 * MB + 64 * KB);         // 32 KB
    unsigned long long* mask   = (unsigned long long*)(ws + 7 * MB + 128 * KB); // 128 KB
    unsigned long long* packed = (unsigned long long*)(ws + 7 * MB + 256 * KB); // 128 KB
    unsigned int* counts       = (unsigned int*)(ws + 7 * MB + 384 * KB); // 256 B
    int* cand                  = (int*)(ws + 8 * MB);                     // 4 MB

    vq_convert_prep<<<dim3(1536),            dim3(256), 0, stream>>>(z, e, (uint32_t*)zb, (uint32_t*)eb, sz_arr, se_arr);
    vq_scan_mfma   <<<dim3(4096),            dim3(256), 0, stream>>>(zb, eb, cmaxb);
    vq_select_mask <<<dim3(NROWS / 4),       dim3(256), 0, stream>>>(cmaxb, mask, packed);
    vq_compact     <<<dim3(NCH),             dim3(256), 0, stream>>>(mask, cand, counts);
    vq_eval        <<<dim3(NCH, EVG),        dim3(256), 0, stream>>>(z, e, sz_arr, se_arr, counts, cand, packed);
    vq_zq          <<<dim3(NROWS * D / 256), dim3(256), 0, stream>>>(z, e, packed, out);
}